// Round 9
// baseline (631.077 us; speedup 1.0000x reference)
//
#include <hip/hip_runtime.h>
#include <math.h>

constexpr int kN    = 100000;
constexpr int kDM   = 256;
constexpr int kDE   = 172;
constexpr int kDT   = 100;
constexpr int kDEMB = 256;
constexpr int kDH   = 128;
constexpr int kH    = 2;
constexpr int kU    = 50000;
constexpr int kNB   = 6000;
constexpr int kK    = 20;
constexpr int kMSG  = 784;
constexpr int kQIN  = kDM + kDT;         // 356
constexpr int kKIN  = kDM + kDE + kDT;   // 528
constexpr int kZIN  = kDEMB + kDM;       // 512
constexpr int kMPAD = 50048;             // 391*128 (GRU M)
constexpr int kKP1  = 832;               // msg K padded
constexpr int kGN   = 768;

constexpr int kNKROWS = kNB * kK;        // 120000
constexpr int kNKPAD  = 120064;          // 938*128
constexpr int kF2V    = 320;             // feats(172)+t2v(100)+pad(48)
constexpr int kQINP   = 384;             // 356 -> 6*64
constexpr int kNBPAD  = 6016;            // 47*128
constexpr int kKVLD   = kKIN + 48;       // 576

typedef __bf16 bf16x8 __attribute__((ext_vector_type(8)));
typedef float  f32x4  __attribute__((ext_vector_type(4)));

__device__ __forceinline__ float sigmoidf_(float x){ return 1.0f/(1.0f+expf(-x)); }

__device__ __forceinline__ unsigned short f2bf(float f){
  unsigned int u = __float_as_uint(f);
  unsigned int r = (u + 0x7FFFu + ((u >> 16) & 1u)) >> 16;
  return (unsigned short)r;
}
__device__ __forceinline__ float bf2f(unsigned short u){
  return __uint_as_float(((unsigned int)u) << 16);
}

// one 8-wide cvt group: fp32 [vrows x vcols](sld) -> bf16 [.. x dld] zero-pad
__device__ __forceinline__ void cvt_group(const float* __restrict__ src,
    unsigned short* __restrict__ dst, int vrows, int vcols, int sld, int dld,
    int r, int c8)
{
  unsigned short o[8];
  if (r < vrows && c8 + 7 < vcols) {
    const float* s = src + (size_t)r * sld + c8;
    const float4 a = *(const float4*)s;
    const float4 b = *(const float4*)(s + 4);
    o[0]=f2bf(a.x); o[1]=f2bf(a.y); o[2]=f2bf(a.z); o[3]=f2bf(a.w);
    o[4]=f2bf(b.x); o[5]=f2bf(b.y); o[6]=f2bf(b.z); o[7]=f2bf(b.w);
  } else if (r < vrows && c8 < vcols) {
    #pragma unroll
    for (int q=0;q<8;q++){
      const int col = c8 + q;
      o[q] = (col < vcols) ? f2bf(src[(size_t)r*sld + col]) : (unsigned short)0;
    }
  } else {
    #pragma unroll
    for (int q=0;q<8;q++) o[q]=0;
  }
  *(uint4*)(dst + (size_t)r*dld + c8) = *(const uint4*)o;
}

// merged: memb (memory -> bf16 [kN x 256]) + A1 (umsg -> bf16 [kMPAD x 832])
__global__ __launch_bounds__(256) void cvt_big2(const float* __restrict__ mem,
    const float* __restrict__ umsg, unsigned short* __restrict__ memb,
    unsigned short* __restrict__ A1)
{
  constexpr int t1 = kN * 32;            // memb groups (g8 = 256/8)
  constexpr int t2 = kMPAD * 104;        // A1 groups (g8 = 832/8)
  const int total = t1 + t2;
  for (int i = blockIdx.x*256 + threadIdx.x; i < total; i += gridDim.x*256) {
    if (i < t1) {
      const int r = i >> 5, c8 = (i & 31) << 3;
      cvt_group(mem, memb, kN, kDM, kDM, kDM, r, c8);
    } else {
      const int j = i - t1;
      const int r = j / 104, c8 = (j - r*104) << 3;
      cvt_group(umsg, A1, kU, kMSG, kMSG, kKP1, r, c8);
    }
  }
}

// merged: all 8 small weight conversions in one launch
__global__ __launch_bounds__(256) void cvt_weights(
    const float* __restrict__ gw_ih, const float* __restrict__ gw_hh,
    const float* __restrict__ w_q, const float* __restrict__ w_k,
    const float* __restrict__ w_v, const float* __restrict__ w_out,
    const float* __restrict__ lp_sw, const float* __restrict__ lp_dw,
    unsigned short* __restrict__ W1b, unsigned short* __restrict__ W2b,
    unsigned short* __restrict__ wq_bf, unsigned short* __restrict__ wkv_bf,
    unsigned short* __restrict__ wo_bf, unsigned short* __restrict__ wlp_bf)
{
  constexpr int n0 = 768*104;
  constexpr int n1 = 768*32;
  constexpr int n2 = 256*48;
  constexpr int n3 = 256*72;
  constexpr int n4 = 256*72;
  constexpr int n5 = 256*64;
  constexpr int n6 = 256*32;
  constexpr int n7 = 256*32;
  constexpr int e0=n0, e1=e0+n1, e2=e1+n2, e3=e2+n3, e4=e3+n4, e5=e4+n5,
                e6=e5+n6, total=e6+n7;
  for (int i = blockIdx.x*256 + threadIdx.x; i < total; i += gridDim.x*256) {
    if (i < e0) {
      const int r = i/104, c8 = (i - r*104) << 3;
      cvt_group(gw_ih, W1b, kGN, kMSG, kMSG, kKP1, r, c8);
    } else if (i < e1) {
      const int j = i - e0, r = j >> 5, c8 = (j & 31) << 3;
      cvt_group(gw_hh, W2b, kGN, kDM, kDM, kDM, r, c8);
    } else if (i < e2) {
      const int j = i - e1, r = j/48, c8 = (j - r*48) << 3;
      cvt_group(w_q, wq_bf, kDEMB, kQIN, kQIN, kQINP, r, c8);
    } else if (i < e3) {
      const int j = i - e2, r = j/72, c8 = (j - r*72) << 3;
      cvt_group(w_k, wkv_bf, kDEMB, kKIN, kKIN, kKVLD, r, c8);
    } else if (i < e4) {
      const int j = i - e3, r = j/72, c8 = (j - r*72) << 3;
      cvt_group(w_v, wkv_bf + (size_t)kDEMB*kKVLD, kDEMB, kKIN, kKIN, kKVLD, r, c8);
    } else if (i < e5) {
      const int j = i - e4, r = j >> 6, c8 = (j & 63) << 3;
      cvt_group(w_out, wo_bf, kDEMB, kZIN, kZIN, kZIN, r, c8);
    } else if (i < e6) {
      const int j = i - e5, r = j >> 5, c8 = (j & 31) << 3;
      cvt_group(lp_sw, wlp_bf, kDEMB, kDEMB, kDEMB, kDEMB, r, c8);
    } else {
      const int j = i - e6, r = j >> 5, c8 = (j & 31) << 3;
      cvt_group(lp_dw, wlp_bf + kDEMB*kDEMB, kDEMB, kDEMB, kDEMB, kDEMB, r, c8);
    }
  }
}

// Generic bf16 GEMM, explicit LDS double-buffer (T3-minimum):
// prefetch K-tile kt+1 via global_load_lds during MFMA of tile kt;
// ONE barrier per tile (compiler emits the vmcnt/lgkm drain at the barrier).
// Optional A-row indirection (gather) and split-A source.
template<int OUT_BF16, int RELU>
__global__ __launch_bounds__(256) void gemm_bt(
    const unsigned short* __restrict__ A0, int lda0,
    const int* __restrict__ aidx, int ksplit, int mvalid,
    const unsigned short* __restrict__ A1p, int lda1,
    const unsigned short* __restrict__ B, int ldb,
    void* __restrict__ Cv, const float* __restrict__ bias,
    int ktiles, int nblk, int ldc)
{
  __shared__ unsigned short smem[4*128*64];   // 2 x (As|Bs), 64 KB
  __shared__ int idxs[128];
  constexpr int kBuf = 2*128*64;              // shorts per buffer

  const int t    = threadIdx.x;
  const int lane = t & 63;
  const int wid  = t >> 6;
  const int wr   = wid >> 1, wc = wid & 1;

  // bijective XCD swizzle
  const int nwg = gridDim.x;
  const int q8  = nwg >> 3, r8 = nwg & 7;
  const int xcd = blockIdx.x & 7, off = blockIdx.x >> 3;
  const int w   = ((xcd < r8) ? xcd*(q8+1) : r8*(q8+1) + (xcd-r8)*q8) + off;
  const int mbase = (w / nblk) * 128;
  const int nbase = (w % nblk) * 128;

  if (aidx && t < 128) {
    const int mr = mbase + t;
    idxs[t] = (mr < mvalid) ? aidx[mr] : 0;
  }
  __syncthreads();

  // hoist per-thread staging rows into registers (4 rows/thread)
  const int srow = t >> 3;
  const int scol = (t & 7) * 8;
  int arow[4];
  #pragma unroll
  for (int it = 0; it < 4; ++it)
    arow[it] = aidx ? idxs[srow + it*32] : (mbase + srow + it*32);

  f32x4 acc[4][4];
  #pragma unroll
  for (int mi=0;mi<4;mi++)
    #pragma unroll
    for (int ni=0;ni<4;ni++)
      acc[mi][ni] = (f32x4){0.f,0.f,0.f,0.f};

  const int lr = (lane & 15);
  const int lk = (lane >> 4) * 8;

  auto stg = [&](int kt, int b){
    const int k0 = kt * 64;
    char* la = (char*)(smem + b*kBuf);
    char* lb = (char*)(smem + b*kBuf + 128*64);
    #pragma unroll
    for (int it = 0; it < 4; ++it) {
      const unsigned short* ga;
      if (kt < ksplit)
        ga = A0 + (size_t)arow[it] * lda0 + k0 + scol;
      else
        ga = A1p + (size_t)(mbase + srow + it*32) * lda1 + (k0 - ksplit*64) + scol;
      const unsigned short* gb = B + (size_t)(nbase + srow + it*32) * ldb + k0 + scol;
      __builtin_amdgcn_global_load_lds(
          (const __attribute__((address_space(1))) void*)ga,
          (__attribute__((address_space(3))) void*)(la + it*4096 + t*16), 16, 0, 0);
      __builtin_amdgcn_global_load_lds(
          (const __attribute__((address_space(1))) void*)gb,
          (__attribute__((address_space(3))) void*)(lb + it*4096 + t*16), 16, 0, 0);
    }
  };

  stg(0, 0);
  __syncthreads();                       // buf0 ready

  for (int kt = 0; kt < ktiles; ++kt) {
    const int cur = kt & 1;
    if (kt + 1 < ktiles) stg(kt + 1, cur ^ 1);   // prefetch next tile
    const unsigned short* As = smem + cur*kBuf;
    const unsigned short* Bs = As + 128*64;
    #pragma unroll
    for (int kk = 0; kk < 64; kk += 32) {
      bf16x8 af[4], bf_[4];
      #pragma unroll
      for (int mi = 0; mi < 4; ++mi)
        af[mi] = *(const bf16x8*)(As + ((wr*64 + mi*16 + lr) * 64 + kk + lk));
      #pragma unroll
      for (int ni = 0; ni < 4; ++ni)
        bf_[ni] = *(const bf16x8*)(Bs + ((wc*64 + ni*16 + lr) * 64 + kk + lk));
      #pragma unroll
      for (int mi = 0; mi < 4; ++mi)
        #pragma unroll
        for (int ni = 0; ni < 4; ++ni)
          acc[mi][ni] = __builtin_amdgcn_mfma_f32_16x16x32_bf16(
              af[mi], bf_[ni], acc[mi][ni], 0, 0, 0);
    }
    __syncthreads();                     // next buf ready + all reads of cur done
  }

  if (OUT_BF16) {
    char* cbytes = (char*)smem;
    #pragma unroll
    for (int mi = 0; mi < 4; ++mi) {
      #pragma unroll
      for (int ni = 0; ni < 4; ++ni) {
        const int col_l = wc*64 + ni*16 + (lane & 15);
        const float bv = bias ? bias[nbase + col_l] : 0.f;
        #pragma unroll
        for (int r = 0; r < 4; ++r) {
          const int row_l = wr*64 + mi*16 + ((lane >> 4) << 2) + r;
          float v = acc[mi][ni][r] + bv;
          if (RELU) v = fmaxf(v, 0.f);
          const int byte = (row_l*256 + col_l*2) ^ ((row_l & 7) << 4);
          *(unsigned short*)(cbytes + byte) = f2bf(v);
        }
      }
    }
    __syncthreads();
    unsigned short* C = (unsigned short*)Cv;
    #pragma unroll
    for (int j = 0; j < 8; ++j) {
      const int idx = j*256 + t;
      const int row = idx >> 4;
      const int col = (idx & 15) * 8;
      const int byte = (row*256 + col*2) ^ ((row & 7) << 4);
      *(uint4*)(C + (size_t)(mbase + row)*ldc + nbase + col) =
          *(const uint4*)(cbytes + byte);
    }
  } else {
    #pragma unroll
    for (int mi = 0; mi < 4; ++mi) {
      #pragma unroll
      for (int ni = 0; ni < 4; ++ni) {
        const int col = nbase + wc*64 + ni*16 + (lane & 15);
        const float bv = bias ? bias[col] : 0.f;
        #pragma unroll
        for (int r = 0; r < 4; ++r) {
          const int row = mbase + wr*64 + mi*16 + ((lane >> 4) << 2) + r;
          float v = acc[mi][ni][r] + bv;
          if (RELU) v = fmaxf(v, 0.f);
          ((float*)Cv)[(size_t)row * ldc + col] = v;
        }
      }
    }
  }
}

// fused GRU gates; writes bf16 rows into the merged memory buffer memb.
__global__ __launch_bounds__(256) void gru_gate_bf(
    const unsigned short* __restrict__ Gi, const unsigned short* __restrict__ Gh,
    const float* __restrict__ memory, const float* __restrict__ b_ih,
    const float* __restrict__ b_hh, const int* __restrict__ unids,
    unsigned short* __restrict__ memb)
{
  const int r = blockIdx.x, j = threadIdx.x;
  const size_t gb = (size_t)r * kGN;
  const float ir  = bf2f(Gi[gb + j])       + b_ih[j];
  const float iz  = bf2f(Gi[gb + 256 + j]) + b_ih[256 + j];
  const float inn = bf2f(Gi[gb + 512 + j]) + b_ih[512 + j];
  const float hr  = bf2f(Gh[gb + j])       + b_hh[j];
  const float hz  = bf2f(Gh[gb + 256 + j]) + b_hh[256 + j];
  const float hn  = bf2f(Gh[gb + 512 + j]) + b_hh[512 + j];
  const int uid = unids[r];
  const float h = memory[(size_t)uid*kDM + j];
  const float rg = sigmoidf_(ir + hr);
  const float zg = sigmoidf_(iz + hz);
  const float ng = tanhf(inn + rg * hn);
  memb[(size_t)uid*kDM + j] = f2bf((1.f - zg) * ng + zg * h);
}

// merged: f2v rows [NKPAD x 320] + qin rows [NBPAD x 384]
__global__ __launch_bounds__(256) void build_both(
    const float* __restrict__ nbr_feats, const float* __restrict__ nbr_times,
    const float* __restrict__ times, const float* __restrict__ last_upd,
    const int* __restrict__ nids,
    const float* __restrict__ t2v_w, const float* __restrict__ t2v_b,
    const unsigned short* __restrict__ memb,
    unsigned short* __restrict__ f2v, unsigned short* __restrict__ qin)
{
  constexpr int t1 = kNKPAD * 40;
  constexpr int t2 = kNBPAD * 48;
  const int total = t1 + t2;
  for (int i = blockIdx.x*256 + threadIdx.x; i < total; i += gridDim.x*256) {
    if (i < t1) {
      const int r  = i / 40;
      const int c8 = (i - r*40) << 3;
      unsigned short o[8];
      if (r >= kNKROWS || c8 >= 272) {
        #pragma unroll
        for (int q=0;q<8;q++) o[q]=0;
      } else if (c8 + 8 <= kDE - 4) {
        const float* s = nbr_feats + (size_t)r*kDE + c8;
        const float4 a = *(const float4*)s;
        const float4 b = *(const float4*)(s + 4);
        o[0]=f2bf(a.x); o[1]=f2bf(a.y); o[2]=f2bf(a.z); o[3]=f2bf(a.w);
        o[4]=f2bf(b.x); o[5]=f2bf(b.y); o[6]=f2bf(b.z); o[7]=f2bf(b.w);
      } else {
        const int n = r / kK;
        const float dlt = nbr_times[r] - (times[n] - last_upd[nids[n]]);
        #pragma unroll
        for (int q=0;q<8;q++){
          const int c = c8 + q;
          float v;
          if (c < kDE)       v = nbr_feats[(size_t)r*kDE + c];
          else if (c < 272)  { const int d = c - kDE; v = cosf(dlt*t2v_w[d] + t2v_b[d]); }
          else               v = 0.f;
          o[q] = f2bf(v);
        }
      }
      *(uint4*)(f2v + (size_t)r*kF2V + c8) = *(const uint4*)o;
    } else {
      const int j  = i - t1;
      const int r  = j / 48;
      const int c8 = (j - r*48) << 3;
      uint4 pack;
      if (r >= kNB) {
        pack = (uint4){0,0,0,0};
      } else if (c8 + 8 <= kDM) {
        pack = *(const uint4*)(memb + (size_t)nids[r]*kDM + c8);
      } else {
        unsigned short o[8];
        #pragma unroll
        for (int q=0;q<8;q++){
          const int c = c8 + q;
          float v = 0.f;
          if (c >= kDM && c < kQIN) v = cosf(t2v_b[c - kDM]);
          o[q] = f2bf(v);
        }
        pack = *(const uint4*)o;
      }
      *(uint4*)(qin + (size_t)r*kQINP + c8) = pack;
    }
  }
}

// Per-row attention core: scores -> softmax -> attn_out; emits [ao|nf] bf16.
__global__ __launch_bounds__(256) void attn2_kernel(
    const float* __restrict__ qv, const unsigned short* __restrict__ kvf,
    const unsigned short* __restrict__ qin, const int* __restrict__ nbr_mask,
    unsigned short* __restrict__ aonf)
{
  __shared__ unsigned short kv[kK][kZIN];
  __shared__ float qv_s[kDEMB];
  __shared__ float red[kH*kK];
  __shared__ float attnw[kH][kK];

  const int n = blockIdx.x;
  const int t = threadIdx.x;

  qv_s[t] = qv[(size_t)n*kDEMB + t];
  {
    const uint4* src = (const uint4*)(kvf + (size_t)n*kK*kZIN);
    uint4* dst = (uint4*)(&kv[0][0]);
    #pragma unroll
    for (int i = 0; i < 5; ++i) dst[t + i*256] = src[t + i*256];
  }
  __syncthreads();

  {
    const int w = t >> 6, lane = t & 63;
    #pragma unroll
    for (int i = 0; i < 10; ++i) {
      const int p = w*10 + i;
      const int h = p / kK, k = p - (p/kK)*kK;
      const int base = h*kDH;
      float s = qv_s[base+lane]*bf2f(kv[k][base+lane])
              + qv_s[base+64+lane]*bf2f(kv[k][base+64+lane]);
      #pragma unroll
      for (int off=32; off; off>>=1) s += __shfl_xor(s, off, 64);
      if (lane == 0) {
        s *= 0.08838834764831845f;
        red[p] = (nbr_mask[(size_t)n*kK + k] > 0) ? s : -1e9f;
      }
    }
  }
  __syncthreads();

  if (t < kH) {
    float m = -1e30f;
    for (int k=0;k<kK;k++) m = fmaxf(m, red[t*kK+k]);
    float e[kK]; float ssum = 0.f;
    for (int k=0;k<kK;k++){ e[k] = expf(red[t*kK+k]-m); ssum += e[k]; }
    const float inv = 1.f/ssum;
    for (int k=0;k<kK;k++) attnw[t][k] = e[k]*inv;
  }
  __syncthreads();

  {
    const int h = t >> 7;
    float acc = 0.f;
    #pragma unroll
    for (int k=0;k<kK;k++) acc += attnw[h][k]*bf2f(kv[k][kDEMB + t]);
    aonf[(size_t)n*kZIN + t] = f2bf(acc);
    aonf[(size_t)n*kZIN + kDEMB + t] = qin[(size_t)n*kQINP + t];
  }
}

// Final link-pred from P = z @ [spw;dpw]^T
__global__ __launch_bounds__(256) void lp_small(
    const float* __restrict__ P, const float* __restrict__ spb,
    const float* __restrict__ dpb, const float* __restrict__ opw,
    const float* __restrict__ opb, float* __restrict__ out)
{
  __shared__ float wsum[4];
  const int b = blockIdx.x;
  const int neg = b / 2000;
  const int i = b - neg*2000;
  const int t = threadIdx.x;
  const int oth = 2000 + neg*2000 + i;
  float h = P[(size_t)i*kZIN + t] + spb[t] + P[(size_t)oth*kZIN + kDEMB + t] + dpb[t];
  float p = fmaxf(h, 0.f) * opw[t];
  #pragma unroll
  for (int off=32; off; off>>=1) p += __shfl_xor(p, off, 64);
  if ((t & 63) == 0) wsum[t>>6] = p;
  __syncthreads();
  if (t == 0)
    out[b] = sigmoidf_(wsum[0]+wsum[1]+wsum[2]+wsum[3] + opb[0]);
}

extern "C" void kernel_launch(void* const* d_in, const int* in_sizes, int n_in,
                              void* d_out, int out_size, void* d_ws, size_t ws_size,
                              hipStream_t stream)
{
  const float* memory   = (const float*)d_in[0];
  const float* last_upd = (const float*)d_in[1];
  const float* umsg     = (const float*)d_in[2];
  const float* times    = (const float*)d_in[3];
  const float* nbr_t    = (const float*)d_in[4];
  const float* nbr_f    = (const float*)d_in[5];
  const float* t2v_w    = (const float*)d_in[6];
  const float* t2v_b    = (const float*)d_in[7];
  const float* gw_ih    = (const float*)d_in[8];
  const float* gw_hh    = (const float*)d_in[9];
  const float* gb_ih    = (const float*)d_in[10];
  const float* gb_hh    = (const float*)d_in[11];
  const float* w_q      = (const float*)d_in[12];
  const float* w_k      = (const float*)d_in[13];
  const float* w_v      = (const float*)d_in[14];
  const float* w_out    = (const float*)d_in[15];
  const float* b_out    = (const float*)d_in[16];
  const float* lp_sw    = (const float*)d_in[17];
  const float* lp_sb    = (const float*)d_in[18];
  const float* lp_dw    = (const float*)d_in[19];
  const float* lp_db    = (const float*)d_in[20];
  const float* lp_ow    = (const float*)d_in[21];
  const float* lp_ob    = (const float*)d_in[22];
  const int*   unids    = (const int*)d_in[23];
  const int*   nids     = (const int*)d_in[24];
  const int*   nbrn     = (const int*)d_in[25];
  const int*   nbrm     = (const int*)d_in[26];

  char* ws = (char*)d_ws;
  unsigned short* memb    = (unsigned short*)ws;                //  51,200,000 B
  unsigned short* f2v     = (unsigned short*)(ws + 51200000);   //  76,840,960
  unsigned short* A1      = (unsigned short*)(ws + 128040960);  //  83,279,872
  unsigned short* W1b     = (unsigned short*)(ws + 211320832);  //   1,277,952
  unsigned short* W2b     = (unsigned short*)(ws + 212598784);  //     393,216
  unsigned short* Gi_bf   = (unsigned short*)(ws + 212992000);  //  76,873,728
  unsigned short* Gh_bf   = (unsigned short*)(ws + 289865728);  //  76,873,728
  unsigned short* kvf_bf  = (unsigned short*)(ws + 366739456);  // 122,945,536
  unsigned short* qin_bf  = (unsigned short*)(ws + 489684992);  //   4,620,288
  float*          qv_f    = (float*)(ws + 494305280);           //   6,160,384
  unsigned short* wq_bf   = (unsigned short*)(ws + 500465664);  //     196,608
  unsigned short* wkv_bf  = (unsigned short*)(ws + 500662272);  //     589,824
  unsigned short* aonf_bf = (unsigned short*)(ws + 501252096);  //   6,160,384
  unsigned short* wo_bf   = (unsigned short*)(ws + 507412480);  //     262,144
  unsigned short* z_bf    = (unsigned short*)(ws + 507674624);  //   3,080,192
  unsigned short* wlp_bf  = (unsigned short*)(ws + 510754816);  //     262,144
  float*          P_f     = (float*)(ws + 511016960);           //  12,320,768
                                                                // end 523,337,728
  cvt_big2<<<2048, 256, 0, stream>>>(memory, umsg, memb, A1);
  cvt_weights<<<728, 256, 0, stream>>>(gw_ih, gw_hh, w_q, w_k, w_v, w_out,
                                       lp_sw, lp_dw,
                                       W1b, W2b, wq_bf, wkv_bf, wo_bf, wlp_bf);

  // --- GRU as bf16 MFMA GEMMs ---
  gemm_bt<1,0><<<(kMPAD/128)*6, 256, 0, stream>>>(
      A1, kKP1, nullptr, 13, kMPAD, A1, kKP1, W1b, kKP1,
      Gi_bf, nullptr, 13, 6, kGN);
  gemm_bt<1,0><<<(kMPAD/128)*6, 256, 0, stream>>>(
      memb, kDM, unids, 4, kU, memb, kDM, W2b, kDM,
      Gh_bf, nullptr, 4, 6, kGN);
  gru_gate_bf<<<kU, 256, 0, stream>>>(Gi_bf, Gh_bf, memory, gb_ih, gb_hh,
                                      unids, memb);

  // --- attention staging (f2v + qin merged) ---
  build_both<<<4096, 256, 0, stream>>>(nbr_f, nbr_t, times, last_upd, nids,
                                       t2v_w, t2v_b, memb, f2v, qin_bf);

  // q projection
  gemm_bt<0,0><<<(kNBPAD/128)*2, 256, 0, stream>>>(
      qin_bf, kQINP, nullptr, 6, kNBPAD, qin_bf, kQINP, wq_bf, kQINP,
      qv_f, nullptr, 6, 2, kDEMB);
  // kv projection with fused virtual k_in: memb-gather (ktiles 0-3) + f2v
  gemm_bt<1,0><<<(kNKPAD/128)*4, 256, 0, stream>>>(
      memb, kDM, nbrn, 4, kNKROWS, f2v, kF2V, wkv_bf, kKVLD,
      kvf_bf, nullptr, 9, 4, kZIN);
  attn2_kernel<<<kNB, 256, 0, stream>>>(qv_f, kvf_bf, qin_bf, nbrm, aonf_bf);
  // z then link-pred projections P = z @ [spw;dpw]^T
  gemm_bt<1,1><<<(kNBPAD/128)*2, 256, 0, stream>>>(
      aonf_bf, kZIN, nullptr, 8, kNBPAD, aonf_bf, kZIN, wo_bf, kZIN,
      z_bf, b_out, 8, 2, kDEMB);
  gemm_bt<0,0><<<(kNBPAD/128)*4, 256, 0, stream>>>(
      z_bf, kDEMB, nullptr, 4, kNBPAD, z_bf, kDEMB, wlp_bf, kDEMB,
      P_f, nullptr, 4, 4, kZIN);
  lp_small<<<4000, 256, 0, stream>>>(P_f, lp_sb, lp_db, lp_ow, lp_ob,
                                     (float*)d_out);
}

// Round 10
// 627.014 us; speedup vs baseline: 1.0065x; 1.0065x over previous
//
#include <hip/hip_runtime.h>
#include <math.h>

constexpr int kN    = 100000;
constexpr int kDM   = 256;
constexpr int kDE   = 172;
constexpr int kDT   = 100;
constexpr int kDEMB = 256;
constexpr int kDH   = 128;
constexpr int kH    = 2;
constexpr int kU    = 50000;
constexpr int kNB   = 6000;
constexpr int kK    = 20;
constexpr int kMSG  = 784;
constexpr int kQIN  = kDM + kDT;         // 356
constexpr int kKIN  = kDM + kDE + kDT;   // 528
constexpr int kZIN  = kDEMB + kDM;       // 512
constexpr int kMPAD = 50048;             // 391*128 (GRU M)
constexpr int kKP1  = 832;               // msg K padded
constexpr int kGN   = 768;

constexpr int kNKROWS = kNB * kK;        // 120000
constexpr int kNKPAD  = 120064;          // 938*128
constexpr int kF2V    = 320;             // feats(172)+t2v(100)+pad(48)
constexpr int kQINP   = 384;             // 356 -> 6*64
constexpr int kNBPAD  = 6016;            // 47*128
constexpr int kKVLD   = kKIN + 48;       // 576

typedef __bf16 bf16x8 __attribute__((ext_vector_type(8)));
typedef float  f32x4  __attribute__((ext_vector_type(4)));

__device__ __forceinline__ float sigmoidf_(float x){ return 1.0f/(1.0f+expf(-x)); }

__device__ __forceinline__ unsigned short f2bf(float f){
  unsigned int u = __float_as_uint(f);
  unsigned int r = (u + 0x7FFFu + ((u >> 16) & 1u)) >> 16;
  return (unsigned short)r;
}
__device__ __forceinline__ float bf2f(unsigned short u){
  return __uint_as_float(((unsigned int)u) << 16);
}

// one 8-wide cvt group: fp32 [vrows x vcols](sld) -> bf16 [.. x dld] zero-pad
__device__ __forceinline__ void cvt_group(const float* __restrict__ src,
    unsigned short* __restrict__ dst, int vrows, int vcols, int sld, int dld,
    int r, int c8)
{
  unsigned short o[8];
  if (r < vrows && c8 + 7 < vcols) {
    const float* s = src + (size_t)r * sld + c8;
    const float4 a = *(const float4*)s;
    const float4 b = *(const float4*)(s + 4);
    o[0]=f2bf(a.x); o[1]=f2bf(a.y); o[2]=f2bf(a.z); o[3]=f2bf(a.w);
    o[4]=f2bf(b.x); o[5]=f2bf(b.y); o[6]=f2bf(b.z); o[7]=f2bf(b.w);
  } else if (r < vrows && c8 < vcols) {
    #pragma unroll
    for (int q=0;q<8;q++){
      const int col = c8 + q;
      o[q] = (col < vcols) ? f2bf(src[(size_t)r*sld + col]) : (unsigned short)0;
    }
  } else {
    #pragma unroll
    for (int q=0;q<8;q++) o[q]=0;
  }
  *(uint4*)(dst + (size_t)r*dld + c8) = *(const uint4*)o;
}

// merged: memb (memory -> bf16 [kN x 256]) + A1 (umsg -> bf16 [kMPAD x 832])
__global__ __launch_bounds__(256) void cvt_big2(const float* __restrict__ mem,
    const float* __restrict__ umsg, unsigned short* __restrict__ memb,
    unsigned short* __restrict__ A1)
{
  constexpr int t1 = kN * 32;            // memb groups (g8 = 256/8)
  constexpr int t2 = kMPAD * 104;        // A1 groups (g8 = 832/8)
  const int total = t1 + t2;
  for (int i = blockIdx.x*256 + threadIdx.x; i < total; i += gridDim.x*256) {
    if (i < t1) {
      const int r = i >> 5, c8 = (i & 31) << 3;
      cvt_group(mem, memb, kN, kDM, kDM, kDM, r, c8);
    } else {
      const int j = i - t1;
      const int r = j / 104, c8 = (j - r*104) << 3;
      cvt_group(umsg, A1, kU, kMSG, kMSG, kKP1, r, c8);
    }
  }
}

// merged: all 8 small weight conversions in one launch
__global__ __launch_bounds__(256) void cvt_weights(
    const float* __restrict__ gw_ih, const float* __restrict__ gw_hh,
    const float* __restrict__ w_q, const float* __restrict__ w_k,
    const float* __restrict__ w_v, const float* __restrict__ w_out,
    const float* __restrict__ lp_sw, const float* __restrict__ lp_dw,
    unsigned short* __restrict__ W1b, unsigned short* __restrict__ W2b,
    unsigned short* __restrict__ wq_bf, unsigned short* __restrict__ wkv_bf,
    unsigned short* __restrict__ wo_bf, unsigned short* __restrict__ wlp_bf)
{
  constexpr int n0 = 768*104;
  constexpr int n1 = 768*32;
  constexpr int n2 = 256*48;
  constexpr int n3 = 256*72;
  constexpr int n4 = 256*72;
  constexpr int n5 = 256*64;
  constexpr int n6 = 256*32;
  constexpr int n7 = 256*32;
  constexpr int e0=n0, e1=e0+n1, e2=e1+n2, e3=e2+n3, e4=e3+n4, e5=e4+n5,
                e6=e5+n6, total=e6+n7;
  for (int i = blockIdx.x*256 + threadIdx.x; i < total; i += gridDim.x*256) {
    if (i < e0) {
      const int r = i/104, c8 = (i - r*104) << 3;
      cvt_group(gw_ih, W1b, kGN, kMSG, kMSG, kKP1, r, c8);
    } else if (i < e1) {
      const int j = i - e0, r = j >> 5, c8 = (j & 31) << 3;
      cvt_group(gw_hh, W2b, kGN, kDM, kDM, kDM, r, c8);
    } else if (i < e2) {
      const int j = i - e1, r = j/48, c8 = (j - r*48) << 3;
      cvt_group(w_q, wq_bf, kDEMB, kQIN, kQIN, kQINP, r, c8);
    } else if (i < e3) {
      const int j = i - e2, r = j/72, c8 = (j - r*72) << 3;
      cvt_group(w_k, wkv_bf, kDEMB, kKIN, kKIN, kKVLD, r, c8);
    } else if (i < e4) {
      const int j = i - e3, r = j/72, c8 = (j - r*72) << 3;
      cvt_group(w_v, wkv_bf + (size_t)kDEMB*kKVLD, kDEMB, kKIN, kKIN, kKVLD, r, c8);
    } else if (i < e5) {
      const int j = i - e4, r = j >> 6, c8 = (j & 63) << 3;
      cvt_group(w_out, wo_bf, kDEMB, kZIN, kZIN, kZIN, r, c8);
    } else if (i < e6) {
      const int j = i - e5, r = j >> 5, c8 = (j & 31) << 3;
      cvt_group(lp_sw, wlp_bf, kDEMB, kDEMB, kDEMB, kDEMB, r, c8);
    } else {
      const int j = i - e6, r = j >> 5, c8 = (j & 31) << 3;
      cvt_group(lp_dw, wlp_bf + kDEMB*kDEMB, kDEMB, kDEMB, kDEMB, kDEMB, r, c8);
    }
  }
}

// Generic bf16 GEMM (round-8 single-buffer structure), LDS exactly 32 KB
// (gather indices live in registers, not LDS -> 5 blocks/CU).
// Optional A-row indirection and split-A source.
template<int OUT_BF16, int RELU>
__global__ __launch_bounds__(256) void gemm_bt(
    const unsigned short* __restrict__ A0, int lda0,
    const int* __restrict__ aidx, int ksplit, int mvalid,
    const unsigned short* __restrict__ A1p, int lda1,
    const unsigned short* __restrict__ B, int ldb,
    void* __restrict__ Cv, const float* __restrict__ bias,
    int ktiles, int nblk, int ldc)
{
  __shared__ unsigned short smem[2*128*64];   // As | Bs (32 KB); C-stage reuse
  unsigned short* As = smem;
  unsigned short* Bs = smem + 128*64;

  const int t    = threadIdx.x;
  const int lane = t & 63;
  const int wid  = t >> 6;
  const int wr   = wid >> 1, wc = wid & 1;

  // bijective XCD swizzle
  const int nwg = gridDim.x;
  const int q8  = nwg >> 3, r8 = nwg & 7;
  const int xcd = blockIdx.x & 7, off = blockIdx.x >> 3;
  const int w   = ((xcd < r8) ? xcd*(q8+1) : r8*(q8+1) + (xcd-r8)*q8) + off;
  const int mbase = (w / nblk) * 128;
  const int nbase = (w % nblk) * 128;

  // per-thread staging rows -> registers (8 lanes share each aidx load)
  const int srow = t >> 3;
  const int scol = (t & 7) * 8;
  int arow[4];
  #pragma unroll
  for (int it = 0; it < 4; ++it) {
    const int mr = mbase + srow + it*32;
    arow[it] = aidx ? ((mr < mvalid) ? aidx[mr] : 0) : mr;
  }

  f32x4 acc[4][4];
  #pragma unroll
  for (int mi=0;mi<4;mi++)
    #pragma unroll
    for (int ni=0;ni<4;ni++)
      acc[mi][ni] = (f32x4){0.f,0.f,0.f,0.f};

  const int lr = (lane & 15);
  const int lk = (lane >> 4) * 8;

  for (int kt = 0; kt < ktiles; ++kt) {
    const int k0 = kt * 64;
    #pragma unroll
    for (int it = 0; it < 4; ++it) {
      const unsigned short* ga;
      if (kt < ksplit)
        ga = A0 + (size_t)arow[it] * lda0 + k0 + scol;
      else
        ga = A1p + (size_t)(mbase + srow + it*32) * lda1 + (k0 - ksplit*64) + scol;
      const unsigned short* gb = B + (size_t)(nbase + srow + it*32) * ldb + k0 + scol;
      __builtin_amdgcn_global_load_lds(
          (const __attribute__((address_space(1))) void*)ga,
          (__attribute__((address_space(3))) void*)((char*)As + it*4096 + t*16),
          16, 0, 0);
      __builtin_amdgcn_global_load_lds(
          (const __attribute__((address_space(1))) void*)gb,
          (__attribute__((address_space(3))) void*)((char*)Bs + it*4096 + t*16),
          16, 0, 0);
    }
    __syncthreads();

    #pragma unroll
    for (int kk = 0; kk < 64; kk += 32) {
      bf16x8 af[4], bf_[4];
      #pragma unroll
      for (int mi = 0; mi < 4; ++mi)
        af[mi] = *(const bf16x8*)(As + ((wr*64 + mi*16 + lr) * 64 + kk + lk));
      #pragma unroll
      for (int ni = 0; ni < 4; ++ni)
        bf_[ni] = *(const bf16x8*)(Bs + ((wc*64 + ni*16 + lr) * 64 + kk + lk));
      #pragma unroll
      for (int mi = 0; mi < 4; ++mi)
        #pragma unroll
        for (int ni = 0; ni < 4; ++ni)
          acc[mi][ni] = __builtin_amdgcn_mfma_f32_16x16x32_bf16(
              af[mi], bf_[ni], acc[mi][ni], 0, 0, 0);
    }
    __syncthreads();
  }

  if (OUT_BF16) {
    char* cbytes = (char*)smem;
    #pragma unroll
    for (int mi = 0; mi < 4; ++mi) {
      #pragma unroll
      for (int ni = 0; ni < 4; ++ni) {
        const int col_l = wc*64 + ni*16 + (lane & 15);
        const float bv = bias ? bias[nbase + col_l] : 0.f;
        #pragma unroll
        for (int r = 0; r < 4; ++r) {
          const int row_l = wr*64 + mi*16 + ((lane >> 4) << 2) + r;
          float v = acc[mi][ni][r] + bv;
          if (RELU) v = fmaxf(v, 0.f);
          const int byte = (row_l*256 + col_l*2) ^ ((row_l & 7) << 4);
          *(unsigned short*)(cbytes + byte) = f2bf(v);
        }
      }
    }
    __syncthreads();
    unsigned short* C = (unsigned short*)Cv;
    #pragma unroll
    for (int j = 0; j < 8; ++j) {
      const int idx = j*256 + t;
      const int row = idx >> 4;
      const int col = (idx & 15) * 8;
      const int byte = (row*256 + col*2) ^ ((row & 7) << 4);
      *(uint4*)(C + (size_t)(mbase + row)*ldc + nbase + col) =
          *(const uint4*)(cbytes + byte);
    }
  } else {
    #pragma unroll
    for (int mi = 0; mi < 4; ++mi) {
      #pragma unroll
      for (int ni = 0; ni < 4; ++ni) {
        const int col = nbase + wc*64 + ni*16 + (lane & 15);
        const float bv = bias ? bias[col] : 0.f;
        #pragma unroll
        for (int r = 0; r < 4; ++r) {
          const int row = mbase + wr*64 + mi*16 + ((lane >> 4) << 2) + r;
          float v = acc[mi][ni][r] + bv;
          if (RELU) v = fmaxf(v, 0.f);
          ((float*)Cv)[(size_t)row * ldc + col] = v;
        }
      }
    }
  }
}

// fused GRU gates; writes bf16 rows into the merged memory buffer memb.
__global__ __launch_bounds__(256) void gru_gate_bf(
    const unsigned short* __restrict__ Gi, const unsigned short* __restrict__ Gh,
    const float* __restrict__ memory, const float* __restrict__ b_ih,
    const float* __restrict__ b_hh, const int* __restrict__ unids,
    unsigned short* __restrict__ memb)
{
  const int r = blockIdx.x, j = threadIdx.x;
  const size_t gb = (size_t)r * kGN;
  const float ir  = bf2f(Gi[gb + j])       + b_ih[j];
  const float iz  = bf2f(Gi[gb + 256 + j]) + b_ih[256 + j];
  const float inn = bf2f(Gi[gb + 512 + j]) + b_ih[512 + j];
  const float hr  = bf2f(Gh[gb + j])       + b_hh[j];
  const float hz  = bf2f(Gh[gb + 256 + j]) + b_hh[256 + j];
  const float hn  = bf2f(Gh[gb + 512 + j]) + b_hh[512 + j];
  const int uid = unids[r];
  const float h = memory[(size_t)uid*kDM + j];
  const float rg = sigmoidf_(ir + hr);
  const float zg = sigmoidf_(iz + hz);
  const float ng = tanhf(inn + rg * hn);
  memb[(size_t)uid*kDM + j] = f2bf((1.f - zg) * ng + zg * h);
}

// merged: f2v rows [NKPAD x 320] + qin rows [NBPAD x 384]
__global__ __launch_bounds__(256) void build_both(
    const float* __restrict__ nbr_feats, const float* __restrict__ nbr_times,
    const float* __restrict__ times, const float* __restrict__ last_upd,
    const int* __restrict__ nids,
    const float* __restrict__ t2v_w, const float* __restrict__ t2v_b,
    const unsigned short* __restrict__ memb,
    unsigned short* __restrict__ f2v, unsigned short* __restrict__ qin)
{
  constexpr int t1 = kNKPAD * 40;
  constexpr int t2 = kNBPAD * 48;
  const int total = t1 + t2;
  for (int i = blockIdx.x*256 + threadIdx.x; i < total; i += gridDim.x*256) {
    if (i < t1) {
      const int r  = i / 40;
      const int c8 = (i - r*40) << 3;
      unsigned short o[8];
      if (r >= kNKROWS || c8 >= 272) {
        #pragma unroll
        for (int q=0;q<8;q++) o[q]=0;
      } else if (c8 + 8 <= kDE - 4) {
        const float* s = nbr_feats + (size_t)r*kDE + c8;
        const float4 a = *(const float4*)s;
        const float4 b = *(const float4*)(s + 4);
        o[0]=f2bf(a.x); o[1]=f2bf(a.y); o[2]=f2bf(a.z); o[3]=f2bf(a.w);
        o[4]=f2bf(b.x); o[5]=f2bf(b.y); o[6]=f2bf(b.z); o[7]=f2bf(b.w);
      } else {
        const int n = r / kK;
        const float dlt = nbr_times[r] - (times[n] - last_upd[nids[n]]);
        #pragma unroll
        for (int q=0;q<8;q++){
          const int c = c8 + q;
          float v;
          if (c < kDE)       v = nbr_feats[(size_t)r*kDE + c];
          else if (c < 272)  { const int d = c - kDE; v = cosf(dlt*t2v_w[d] + t2v_b[d]); }
          else               v = 0.f;
          o[q] = f2bf(v);
        }
      }
      *(uint4*)(f2v + (size_t)r*kF2V + c8) = *(const uint4*)o;
    } else {
      const int j  = i - t1;
      const int r  = j / 48;
      const int c8 = (j - r*48) << 3;
      uint4 pack;
      if (r >= kNB) {
        pack = (uint4){0,0,0,0};
      } else if (c8 + 8 <= kDM) {
        pack = *(const uint4*)(memb + (size_t)nids[r]*kDM + c8);
      } else {
        unsigned short o[8];
        #pragma unroll
        for (int q=0;q<8;q++){
          const int c = c8 + q;
          float v = 0.f;
          if (c >= kDM && c < kQIN) v = cosf(t2v_b[c - kDM]);
          o[q] = f2bf(v);
        }
        pack = *(const uint4*)o;
      }
      *(uint4*)(qin + (size_t)r*kQINP + c8) = pack;
    }
  }
}

// Per-row attention core: scores -> softmax -> attn_out; emits [ao|nf] bf16.
__global__ __launch_bounds__(256) void attn2_kernel(
    const float* __restrict__ qv, const unsigned short* __restrict__ kvf,
    const unsigned short* __restrict__ qin, const int* __restrict__ nbr_mask,
    unsigned short* __restrict__ aonf)
{
  __shared__ unsigned short kv[kK][kZIN];
  __shared__ float qv_s[kDEMB];
  __shared__ float red[kH*kK];
  __shared__ float attnw[kH][kK];

  const int n = blockIdx.x;
  const int t = threadIdx.x;

  qv_s[t] = qv[(size_t)n*kDEMB + t];
  {
    const uint4* src = (const uint4*)(kvf + (size_t)n*kK*kZIN);
    uint4* dst = (uint4*)(&kv[0][0]);
    #pragma unroll
    for (int i = 0; i < 5; ++i) dst[t + i*256] = src[t + i*256];
  }
  __syncthreads();

  {
    const int w = t >> 6, lane = t & 63;
    #pragma unroll
    for (int i = 0; i < 10; ++i) {
      const int p = w*10 + i;
      const int h = p / kK, k = p - (p/kK)*kK;
      const int base = h*kDH;
      float s = qv_s[base+lane]*bf2f(kv[k][base+lane])
              + qv_s[base+64+lane]*bf2f(kv[k][base+64+lane]);
      #pragma unroll
      for (int off=32; off; off>>=1) s += __shfl_xor(s, off, 64);
      if (lane == 0) {
        s *= 0.08838834764831845f;
        red[p] = (nbr_mask[(size_t)n*kK + k] > 0) ? s : -1e9f;
      }
    }
  }
  __syncthreads();

  if (t < kH) {
    float m = -1e30f;
    for (int k=0;k<kK;k++) m = fmaxf(m, red[t*kK+k]);
    float e[kK]; float ssum = 0.f;
    for (int k=0;k<kK;k++){ e[k] = expf(red[t*kK+k]-m); ssum += e[k]; }
    const float inv = 1.f/ssum;
    for (int k=0;k<kK;k++) attnw[t][k] = e[k]*inv;
  }
  __syncthreads();

  {
    const int h = t >> 7;
    float acc = 0.f;
    #pragma unroll
    for (int k=0;k<kK;k++) acc += attnw[h][k]*bf2f(kv[k][kDEMB + t]);
    aonf[(size_t)n*kZIN + t] = f2bf(acc);
    aonf[(size_t)n*kZIN + kDEMB + t] = qin[(size_t)n*kQINP + t];
  }
}

// Final link-pred from P = z @ [spw;dpw]^T
__global__ __launch_bounds__(256) void lp_small(
    const float* __restrict__ P, const float* __restrict__ spb,
    const float* __restrict__ dpb, const float* __restrict__ opw,
    const float* __restrict__ opb, float* __restrict__ out)
{
  __shared__ float wsum[4];
  const int b = blockIdx.x;
  const int neg = b / 2000;
  const int i = b - neg*2000;
  const int t = threadIdx.x;
  const int oth = 2000 + neg*2000 + i;
  float h = P[(size_t)i*kZIN + t] + spb[t] + P[(size_t)oth*kZIN + kDEMB + t] + dpb[t];
  float p = fmaxf(h, 0.f) * opw[t];
  #pragma unroll
  for (int off=32; off; off>>=1) p += __shfl_xor(p, off, 64);
  if ((t & 63) == 0) wsum[t>>6] = p;
  __syncthreads();
  if (t == 0)
    out[b] = sigmoidf_(wsum[0]+wsum[1]+wsum[2]+wsum[3] + opb[0]);
}

extern "C" void kernel_launch(void* const* d_in, const int* in_sizes, int n_in,
                              void* d_out, int out_size, void* d_ws, size_t ws_size,
                              hipStream_t stream)
{
  const float* memory   = (const float*)d_in[0];
  const float* last_upd = (const float*)d_in[1];
  const float* umsg     = (const float*)d_in[2];
  const float* times    = (const float*)d_in[3];
  const float* nbr_t    = (const float*)d_in[4];
  const float* nbr_f    = (const float*)d_in[5];
  const float* t2v_w    = (const float*)d_in[6];
  const float* t2v_b    = (const float*)d_in[7];
  const float* gw_ih    = (const float*)d_in[8];
  const float* gw_hh    = (const float*)d_in[9];
  const float* gb_ih    = (const float*)d_in[10];
  const float* gb_hh    = (const float*)d_in[11];
  const float* w_q      = (const float*)d_in[12];
  const float* w_k      = (const float*)d_in[13];
  const float* w_v      = (const float*)d_in[14];
  const float* w_out    = (const float*)d_in[15];
  const float* b_out    = (const float*)d_in[16];
  const float* lp_sw    = (const float*)d_in[17];
  const float* lp_sb    = (const float*)d_in[18];
  const float* lp_dw    = (const float*)d_in[19];
  const float* lp_db    = (const float*)d_in[20];
  const float* lp_ow    = (const float*)d_in[21];
  const float* lp_ob    = (const float*)d_in[22];
  const int*   unids    = (const int*)d_in[23];
  const int*   nids     = (const int*)d_in[24];
  const int*   nbrn     = (const int*)d_in[25];
  const int*   nbrm     = (const int*)d_in[26];

  char* ws = (char*)d_ws;
  unsigned short* memb    = (unsigned short*)ws;                //  51,200,000 B
  unsigned short* f2v     = (unsigned short*)(ws + 51200000);   //  76,840,960
  unsigned short* A1      = (unsigned short*)(ws + 128040960);  //  83,279,872
  unsigned short* W1b     = (unsigned short*)(ws + 211320832);  //   1,277,952
  unsigned short* W2b     = (unsigned short*)(ws + 212598784);  //     393,216
  unsigned short* Gi_bf   = (unsigned short*)(ws + 212992000);  //  76,873,728
  unsigned short* Gh_bf   = (unsigned short*)(ws + 289865728);  //  76,873,728
  unsigned short* kvf_bf  = (unsigned short*)(ws + 366739456);  // 122,945,536
  unsigned short* qin_bf  = (unsigned short*)(ws + 489684992);  //   4,620,288
  float*          qv_f    = (float*)(ws + 494305280);           //   6,160,384
  unsigned short* wq_bf   = (unsigned short*)(ws + 500465664);  //     196,608
  unsigned short* wkv_bf  = (unsigned short*)(ws + 500662272);  //     589,824
  unsigned short* aonf_bf = (unsigned short*)(ws + 501252096);  //   6,160,384
  unsigned short* wo_bf   = (unsigned short*)(ws + 507412480);  //     262,144
  unsigned short* z_bf    = (unsigned short*)(ws + 507674624);  //   3,080,192
  unsigned short* wlp_bf  = (unsigned short*)(ws + 510754816);  //     262,144
  float*          P_f     = (float*)(ws + 511016960);           //  12,320,768
                                                                // end 523,337,728
  cvt_big2<<<2048, 256, 0, stream>>>(memory, umsg, memb, A1);
  cvt_weights<<<728, 256, 0, stream>>>(gw_ih, gw_hh, w_q, w_k, w_v, w_out,
                                       lp_sw, lp_dw,
                                       W1b, W2b, wq_bf, wkv_bf, wo_bf, wlp_bf);

  // --- GRU as bf16 MFMA GEMMs ---
  gemm_bt<1,0><<<(kMPAD/128)*6, 256, 0, stream>>>(
      A1, kKP1, nullptr, 13, kMPAD, A1, kKP1, W1b, kKP1,
      Gi_bf, nullptr, 13, 6, kGN);
  gemm_bt<1,0><<<(kMPAD/128)*6, 256, 0, stream>>>(
      memb, kDM, unids, 4, kU, memb, kDM, W2b, kDM,
      Gh_bf, nullptr, 4, 6, kGN);
  gru_gate_bf<<<kU, 256, 0, stream>>>(Gi_bf, Gh_bf, memory, gb_ih, gb_hh,
                                      unids, memb);

  // --- attention staging (f2v + qin merged) ---
  build_both<<<4096, 256, 0, stream>>>(nbr_f, nbr_t, times, last_upd, nids,
                                       t2v_w, t2v_b, memb, f2v, qin_bf);

  // q projection
  gemm_bt<0,0><<<(kNBPAD/128)*2, 256, 0, stream>>>(
      qin_bf, kQINP, nullptr, 6, kNBPAD, qin_bf, kQINP, wq_bf, kQINP,
      qv_f, nullptr, 6, 2, kDEMB);
  // kv projection with fused virtual k_in: memb-gather (ktiles 0-3) + f2v
  gemm_bt<1,0><<<(kNKPAD/128)*4, 256, 0, stream>>>(
      memb, kDM, nbrn, 4, kNKROWS, f2v, kF2V, wkv_bf, kKVLD,
      kvf_bf, nullptr, 9, 4, kZIN);
  attn2_kernel<<<kNB, 256, 0, stream>>>(qv_f, kvf_bf, qin_bf, nbrm, aonf_bf);
  // z then link-pred projections P = z @ [spw;dpw]^T
  gemm_bt<1,1><<<(kNBPAD/128)*2, 256, 0, stream>>>(
      aonf_bf, kZIN, nullptr, 8, kNBPAD, aonf_bf, kZIN, wo_bf, kZIN,
      z_bf, b_out, 8, 2, kDEMB);
  gemm_bt<0,0><<<(kNBPAD/128)*4, 256, 0, stream>>>(
      z_bf, kDEMB, nullptr, 4, kNBPAD, z_bf, kDEMB, wlp_bf, kDEMB,
      P_f, nullptr, 4, 4, kZIN);
  lp_small<<<4000, 256, 0, stream>>>(P_f, lp_sb, lp_db, lp_ow, lp_ob,
                                     (float*)d_out);
}

// Round 11
// 574.794 us; speedup vs baseline: 1.0979x; 1.0909x over previous
//
#include <hip/hip_runtime.h>
#include <math.h>

constexpr int kN    = 100000;
constexpr int kDM   = 256;
constexpr int kDE   = 172;
constexpr int kDT   = 100;
constexpr int kDEMB = 256;
constexpr int kDH   = 128;
constexpr int kH    = 2;
constexpr int kU    = 50000;
constexpr int kNB   = 6000;
constexpr int kK    = 20;
constexpr int kMSG  = 784;
constexpr int kQIN  = kDM + kDT;         // 356
constexpr int kKIN  = kDM + kDE + kDT;   // 528
constexpr int kZIN  = kDEMB + kDM;       // 512
constexpr int kMPAD = 50048;             // 391*128 (GRU M)
constexpr int kKP1  = 832;               // msg K padded
constexpr int kGN   = 768;

constexpr int kNKROWS = kNB * kK;        // 120000
constexpr int kNKPAD  = 120064;          // 938*128
constexpr int kF2V    = 320;             // feats(172)+t2v(100)+pad(48)
constexpr int kQINP   = 384;             // 356 -> 6*64
constexpr int kNBPAD  = 6016;            // 47*128
constexpr int kKVLD   = kKIN + 48;       // 576

typedef __bf16 bf16x8 __attribute__((ext_vector_type(8)));
typedef float  f32x4  __attribute__((ext_vector_type(4)));

__device__ __forceinline__ float sigmoidf_(float x){ return 1.0f/(1.0f+expf(-x)); }

__device__ __forceinline__ unsigned short f2bf(float f){
  unsigned int u = __float_as_uint(f);
  unsigned int r = (u + 0x7FFFu + ((u >> 16) & 1u)) >> 16;
  return (unsigned short)r;
}
__device__ __forceinline__ float bf2f(unsigned short u){
  return __uint_as_float(((unsigned int)u) << 16);
}

// one 8-wide cvt group: fp32 [vrows x vcols](sld) -> bf16 [.. x dld] zero-pad
__device__ __forceinline__ void cvt_group(const float* __restrict__ src,
    unsigned short* __restrict__ dst, int vrows, int vcols, int sld, int dld,
    int r, int c8)
{
  unsigned short o[8];
  if (r < vrows && c8 + 7 < vcols) {
    const float* s = src + (size_t)r * sld + c8;
    const float4 a = *(const float4*)s;
    const float4 b = *(const float4*)(s + 4);
    o[0]=f2bf(a.x); o[1]=f2bf(a.y); o[2]=f2bf(a.z); o[3]=f2bf(a.w);
    o[4]=f2bf(b.x); o[5]=f2bf(b.y); o[6]=f2bf(b.z); o[7]=f2bf(b.w);
  } else if (r < vrows && c8 < vcols) {
    #pragma unroll
    for (int q=0;q<8;q++){
      const int col = c8 + q;
      o[q] = (col < vcols) ? f2bf(src[(size_t)r*sld + col]) : (unsigned short)0;
    }
  } else {
    #pragma unroll
    for (int q=0;q<8;q++) o[q]=0;
  }
  *(uint4*)(dst + (size_t)r*dld + c8) = *(const uint4*)o;
}

// merged: memb (memory -> bf16 [kN x 256]) + A1 (umsg -> bf16 [kMPAD x 832])
__global__ __launch_bounds__(256) void cvt_big2(const float* __restrict__ mem,
    const float* __restrict__ umsg, unsigned short* __restrict__ memb,
    unsigned short* __restrict__ A1)
{
  constexpr int t1 = kN * 32;            // memb groups (g8 = 256/8)
  constexpr int t2 = kMPAD * 104;        // A1 groups (g8 = 832/8)
  const int total = t1 + t2;
  for (int i = blockIdx.x*256 + threadIdx.x; i < total; i += gridDim.x*256) {
    if (i < t1) {
      const int r = i >> 5, c8 = (i & 31) << 3;
      cvt_group(mem, memb, kN, kDM, kDM, kDM, r, c8);
    } else {
      const int j = i - t1;
      const int r = j / 104, c8 = (j - r*104) << 3;
      cvt_group(umsg, A1, kU, kMSG, kMSG, kKP1, r, c8);
    }
  }
}

// merged: all 8 small weight conversions in one launch
__global__ __launch_bounds__(256) void cvt_weights(
    const float* __restrict__ gw_ih, const float* __restrict__ gw_hh,
    const float* __restrict__ w_q, const float* __restrict__ w_k,
    const float* __restrict__ w_v, const float* __restrict__ w_out,
    const float* __restrict__ lp_sw, const float* __restrict__ lp_dw,
    unsigned short* __restrict__ W1b, unsigned short* __restrict__ W2b,
    unsigned short* __restrict__ wq_bf, unsigned short* __restrict__ wkv_bf,
    unsigned short* __restrict__ wo_bf, unsigned short* __restrict__ wlp_bf)
{
  constexpr int n0 = 768*104;
  constexpr int n1 = 768*32;
  constexpr int n2 = 256*48;
  constexpr int n3 = 256*72;
  constexpr int n4 = 256*72;
  constexpr int n5 = 256*64;
  constexpr int n6 = 256*32;
  constexpr int n7 = 256*32;
  constexpr int e0=n0, e1=e0+n1, e2=e1+n2, e3=e2+n3, e4=e3+n4, e5=e4+n5,
                e6=e5+n6, total=e6+n7;
  for (int i = blockIdx.x*256 + threadIdx.x; i < total; i += gridDim.x*256) {
    if (i < e0) {
      const int r = i/104, c8 = (i - r*104) << 3;
      cvt_group(gw_ih, W1b, kGN, kMSG, kMSG, kKP1, r, c8);
    } else if (i < e1) {
      const int j = i - e0, r = j >> 5, c8 = (j & 31) << 3;
      cvt_group(gw_hh, W2b, kGN, kDM, kDM, kDM, r, c8);
    } else if (i < e2) {
      const int j = i - e1, r = j/48, c8 = (j - r*48) << 3;
      cvt_group(w_q, wq_bf, kDEMB, kQIN, kQIN, kQINP, r, c8);
    } else if (i < e3) {
      const int j = i - e2, r = j/72, c8 = (j - r*72) << 3;
      cvt_group(w_k, wkv_bf, kDEMB, kKIN, kKIN, kKVLD, r, c8);
    } else if (i < e4) {
      const int j = i - e3, r = j/72, c8 = (j - r*72) << 3;
      cvt_group(w_v, wkv_bf + (size_t)kDEMB*kKVLD, kDEMB, kKIN, kKIN, kKVLD, r, c8);
    } else if (i < e5) {
      const int j = i - e4, r = j >> 6, c8 = (j & 63) << 3;
      cvt_group(w_out, wo_bf, kDEMB, kZIN, kZIN, kZIN, r, c8);
    } else if (i < e6) {
      const int j = i - e5, r = j >> 5, c8 = (j & 31) << 3;
      cvt_group(lp_sw, wlp_bf, kDEMB, kDEMB, kDEMB, kDEMB, r, c8);
    } else {
      const int j = i - e6, r = j >> 5, c8 = (j & 31) << 3;
      cvt_group(lp_dw, wlp_bf + kDEMB*kDEMB, kDEMB, kDEMB, kDEMB, kDEMB, r, c8);
    }
  }
}

// Generic bf16 GEMM with optional A-row indirection and split-A source.
// Round-8 proven structure: single-buffer, idxs in LDS, 80 VGPR.
// OUT_BF16 path: LDS-staged coalesced epilogue.
template<int OUT_BF16, int RELU>
__global__ __launch_bounds__(256) void gemm_bt(
    const unsigned short* __restrict__ A0, int lda0,
    const int* __restrict__ aidx, int ksplit, int mvalid,
    const unsigned short* __restrict__ A1p, int lda1,
    const unsigned short* __restrict__ B, int ldb,
    void* __restrict__ Cv, const float* __restrict__ bias,
    int ktiles, int nblk, int ldc)
{
  __shared__ unsigned short smem[2*128*64];   // As | Bs; reused as C-stage
  unsigned short* As = smem;
  unsigned short* Bs = smem + 128*64;
  __shared__ int idxs[128];

  const int t    = threadIdx.x;
  const int lane = t & 63;
  const int wid  = t >> 6;
  const int wr   = wid >> 1, wc = wid & 1;

  // bijective XCD swizzle
  const int nwg = gridDim.x;
  const int q8  = nwg >> 3, r8 = nwg & 7;
  const int xcd = blockIdx.x & 7, off = blockIdx.x >> 3;
  const int w   = ((xcd < r8) ? xcd*(q8+1) : r8*(q8+1) + (xcd-r8)*q8) + off;
  const int mbase = (w / nblk) * 128;
  const int nbase = (w % nblk) * 128;

  if (aidx && t < 128) {
    const int mr = mbase + t;
    idxs[t] = (mr < mvalid) ? aidx[mr] : 0;
  }
  __syncthreads();

  f32x4 acc[4][4];
  #pragma unroll
  for (int mi=0;mi<4;mi++)
    #pragma unroll
    for (int ni=0;ni<4;ni++)
      acc[mi][ni] = (f32x4){0.f,0.f,0.f,0.f};

  const int lr = (lane & 15);
  const int lk = (lane >> 4) * 8;

  for (int kt = 0; kt < ktiles; ++kt) {
    const int k0 = kt * 64;
    #pragma unroll
    for (int it = 0; it < 4; ++it) {
      const int row = (t >> 3) + it * 32;
      const int col = (t & 7) * 8;
      const unsigned short* ga;
      if (kt < ksplit) {
        const int ridx = aidx ? idxs[row] : (mbase + row);
        ga = A0 + (size_t)ridx * lda0 + k0 + col;
      } else {
        ga = A1p + (size_t)(mbase + row) * lda1 + (k0 - ksplit*64) + col;
      }
      const unsigned short* gb = B + (size_t)(nbase + row) * ldb + k0 + col;
      char* la = (char*)As + it*4096 + t*16;
      char* lb = (char*)Bs + it*4096 + t*16;
      __builtin_amdgcn_global_load_lds(
          (const __attribute__((address_space(1))) void*)ga,
          (__attribute__((address_space(3))) void*)la, 16, 0, 0);
      __builtin_amdgcn_global_load_lds(
          (const __attribute__((address_space(1))) void*)gb,
          (__attribute__((address_space(3))) void*)lb, 16, 0, 0);
    }
    __syncthreads();

    #pragma unroll
    for (int kk = 0; kk < 64; kk += 32) {
      bf16x8 af[4], bf_[4];
      #pragma unroll
      for (int mi = 0; mi < 4; ++mi)
        af[mi] = *(const bf16x8*)(As + ((wr*64 + mi*16 + lr) * 64 + kk + lk));
      #pragma unroll
      for (int ni = 0; ni < 4; ++ni)
        bf_[ni] = *(const bf16x8*)(Bs + ((wc*64 + ni*16 + lr) * 64 + kk + lk));
      #pragma unroll
      for (int mi = 0; mi < 4; ++mi)
        #pragma unroll
        for (int ni = 0; ni < 4; ++ni)
          acc[mi][ni] = __builtin_amdgcn_mfma_f32_16x16x32_bf16(
              af[mi], bf_[ni], acc[mi][ni], 0, 0, 0);
    }
    __syncthreads();
  }

  if (OUT_BF16) {
    char* cbytes = (char*)smem;
    #pragma unroll
    for (int mi = 0; mi < 4; ++mi) {
      #pragma unroll
      for (int ni = 0; ni < 4; ++ni) {
        const int col_l = wc*64 + ni*16 + (lane & 15);
        const float bv = bias ? bias[nbase + col_l] : 0.f;
        #pragma unroll
        for (int r = 0; r < 4; ++r) {
          const int row_l = wr*64 + mi*16 + ((lane >> 4) << 2) + r;
          float v = acc[mi][ni][r] + bv;
          if (RELU) v = fmaxf(v, 0.f);
          const int byte = (row_l*256 + col_l*2) ^ ((row_l & 7) << 4);
          *(unsigned short*)(cbytes + byte) = f2bf(v);
        }
      }
    }
    __syncthreads();
    unsigned short* C = (unsigned short*)Cv;
    #pragma unroll
    for (int j = 0; j < 8; ++j) {
      const int idx = j*256 + t;
      const int row = idx >> 4;
      const int col = (idx & 15) * 8;
      const int byte = (row*256 + col*2) ^ ((row & 7) << 4);
      *(uint4*)(C + (size_t)(mbase + row)*ldc + nbase + col) =
          *(const uint4*)(cbytes + byte);
    }
  } else {
    #pragma unroll
    for (int mi = 0; mi < 4; ++mi) {
      #pragma unroll
      for (int ni = 0; ni < 4; ++ni) {
        const int col = nbase + wc*64 + ni*16 + (lane & 15);
        const float bv = bias ? bias[col] : 0.f;
        #pragma unroll
        for (int r = 0; r < 4; ++r) {
          const int row = mbase + wr*64 + mi*16 + ((lane >> 4) << 2) + r;
          float v = acc[mi][ni][r] + bv;
          if (RELU) v = fmaxf(v, 0.f);
          ((float*)Cv)[(size_t)row * ldc + col] = v;
        }
      }
    }
  }
}

// fused GRU gates; writes bf16 rows into the merged memory buffer memb.
__global__ __launch_bounds__(256) void gru_gate_bf(
    const unsigned short* __restrict__ Gi, const unsigned short* __restrict__ Gh,
    const float* __restrict__ memory, const float* __restrict__ b_ih,
    const float* __restrict__ b_hh, const int* __restrict__ unids,
    unsigned short* __restrict__ memb)
{
  const int r = blockIdx.x, j = threadIdx.x;
  const size_t gb = (size_t)r * kGN;
  const float ir  = bf2f(Gi[gb + j])       + b_ih[j];
  const float iz  = bf2f(Gi[gb + 256 + j]) + b_ih[256 + j];
  const float inn = bf2f(Gi[gb + 512 + j]) + b_ih[512 + j];
  const float hr  = bf2f(Gh[gb + j])       + b_hh[j];
  const float hz  = bf2f(Gh[gb + 256 + j]) + b_hh[256 + j];
  const float hn  = bf2f(Gh[gb + 512 + j]) + b_hh[512 + j];
  const int uid = unids[r];
  const float h = memory[(size_t)uid*kDM + j];
  const float rg = sigmoidf_(ir + hr);
  const float zg = sigmoidf_(iz + hz);
  const float ng = tanhf(inn + rg * hn);
  memb[(size_t)uid*kDM + j] = f2bf((1.f - zg) * ng + zg * h);
}

// merged: f2v rows [NKPAD x 320] + qin rows [NBPAD x 384]
__global__ __launch_bounds__(256) void build_both(
    const float* __restrict__ nbr_feats, const float* __restrict__ nbr_times,
    const float* __restrict__ times, const float* __restrict__ last_upd,
    const int* __restrict__ nids,
    const float* __restrict__ t2v_w, const float* __restrict__ t2v_b,
    const unsigned short* __restrict__ memb,
    unsigned short* __restrict__ f2v, unsigned short* __restrict__ qin)
{
  constexpr int t1 = kNKPAD * 40;
  constexpr int t2 = kNBPAD * 48;
  const int total = t1 + t2;
  for (int i = blockIdx.x*256 + threadIdx.x; i < total; i += gridDim.x*256) {
    if (i < t1) {
      const int r  = i / 40;
      const int c8 = (i - r*40) << 3;
      unsigned short o[8];
      if (r >= kNKROWS || c8 >= 272) {
        #pragma unroll
        for (int q=0;q<8;q++) o[q]=0;
      } else if (c8 + 8 <= kDE - 4) {
        const float* s = nbr_feats + (size_t)r*kDE + c8;
        const float4 a = *(const float4*)s;
        const float4 b = *(const float4*)(s + 4);
        o[0]=f2bf(a.x); o[1]=f2bf(a.y); o[2]=f2bf(a.z); o[3]=f2bf(a.w);
        o[4]=f2bf(b.x); o[5]=f2bf(b.y); o[6]=f2bf(b.z); o[7]=f2bf(b.w);
      } else {
        const int n = r / kK;
        const float dlt = nbr_times[r] - (times[n] - last_upd[nids[n]]);
        #pragma unroll
        for (int q=0;q<8;q++){
          const int c = c8 + q;
          float v;
          if (c < kDE)       v = nbr_feats[(size_t)r*kDE + c];
          else if (c < 272)  { const int d = c - kDE; v = cosf(dlt*t2v_w[d] + t2v_b[d]); }
          else               v = 0.f;
          o[q] = f2bf(v);
        }
      }
      *(uint4*)(f2v + (size_t)r*kF2V + c8) = *(const uint4*)o;
    } else {
      const int j  = i - t1;
      const int r  = j / 48;
      const int c8 = (j - r*48) << 3;
      uint4 pack;
      if (r >= kNB) {
        pack = (uint4){0,0,0,0};
      } else if (c8 + 8 <= kDM) {
        pack = *(const uint4*)(memb + (size_t)nids[r]*kDM + c8);
      } else {
        unsigned short o[8];
        #pragma unroll
        for (int q=0;q<8;q++){
          const int c = c8 + q;
          float v = 0.f;
          if (c >= kDM && c < kQIN) v = cosf(t2v_b[c - kDM]);
          o[q] = f2bf(v);
        }
        pack = *(const uint4*)o;
      }
      *(uint4*)(qin + (size_t)r*kQINP + c8) = pack;
    }
  }
}

// Per-row attention core: scores -> softmax -> attn_out; emits [ao|nf] bf16.
__global__ __launch_bounds__(256) void attn2_kernel(
    const float* __restrict__ qv, const unsigned short* __restrict__ kvf,
    const unsigned short* __restrict__ qin, const int* __restrict__ nbr_mask,
    unsigned short* __restrict__ aonf)
{
  __shared__ unsigned short kv[kK][kZIN];
  __shared__ float qv_s[kDEMB];
  __shared__ float red[kH*kK];
  __shared__ float attnw[kH][kK];

  const int n = blockIdx.x;
  const int t = threadIdx.x;

  qv_s[t] = qv[(size_t)n*kDEMB + t];
  {
    const uint4* src = (const uint4*)(kvf + (size_t)n*kK*kZIN);
    uint4* dst = (uint4*)(&kv[0][0]);
    #pragma unroll
    for (int i = 0; i < 5; ++i) dst[t + i*256] = src[t + i*256];
  }
  __syncthreads();

  {
    const int w = t >> 6, lane = t & 63;
    #pragma unroll
    for (int i = 0; i < 10; ++i) {
      const int p = w*10 + i;
      const int h = p / kK, k = p - (p/kK)*kK;
      const int base = h*kDH;
      float s = qv_s[base+lane]*bf2f(kv[k][base+lane])
              + qv_s[base+64+lane]*bf2f(kv[k][base+64+lane]);
      #pragma unroll
      for (int off=32; off; off>>=1) s += __shfl_xor(s, off, 64);
      if (lane == 0) {
        s *= 0.08838834764831845f;
        red[p] = (nbr_mask[(size_t)n*kK + k] > 0) ? s : -1e9f;
      }
    }
  }
  __syncthreads();

  if (t < kH) {
    float m = -1e30f;
    for (int k=0;k<kK;k++) m = fmaxf(m, red[t*kK+k]);
    float e[kK]; float ssum = 0.f;
    for (int k=0;k<kK;k++){ e[k] = expf(red[t*kK+k]-m); ssum += e[k]; }
    const float inv = 1.f/ssum;
    for (int k=0;k<kK;k++) attnw[t][k] = e[k]*inv;
  }
  __syncthreads();

  {
    const int h = t >> 7;
    float acc = 0.f;
    #pragma unroll
    for (int k=0;k<kK;k++) acc += attnw[h][k]*bf2f(kv[k][kDEMB + t]);
    aonf[(size_t)n*kZIN + t] = f2bf(acc);
    aonf[(size_t)n*kZIN + kDEMB + t] = qin[(size_t)n*kQINP + t];
  }
}

// Final link-pred from P = z @ [spw;dpw]^T
__global__ __launch_bounds__(256) void lp_small(
    const float* __restrict__ P, const float* __restrict__ spb,
    const float* __restrict__ dpb, const float* __restrict__ opw,
    const float* __restrict__ opb, float* __restrict__ out)
{
  __shared__ float wsum[4];
  const int b = blockIdx.x;
  const int neg = b / 2000;
  const int i = b - neg*2000;
  const int t = threadIdx.x;
  const int oth = 2000 + neg*2000 + i;
  float h = P[(size_t)i*kZIN + t] + spb[t] + P[(size_t)oth*kZIN + kDEMB + t] + dpb[t];
  float p = fmaxf(h, 0.f) * opw[t];
  #pragma unroll
  for (int off=32; off; off>>=1) p += __shfl_xor(p, off, 64);
  if ((t & 63) == 0) wsum[t>>6] = p;
  __syncthreads();
  if (t == 0)
    out[b] = sigmoidf_(wsum[0]+wsum[1]+wsum[2]+wsum[3] + opb[0]);
}

extern "C" void kernel_launch(void* const* d_in, const int* in_sizes, int n_in,
                              void* d_out, int out_size, void* d_ws, size_t ws_size,
                              hipStream_t stream)
{
  const float* memory   = (const float*)d_in[0];
  const float* last_upd = (const float*)d_in[1];
  const float* umsg     = (const float*)d_in[2];
  const float* times    = (const float*)d_in[3];
  const float* nbr_t    = (const float*)d_in[4];
  const float* nbr_f    = (const float*)d_in[5];
  const float* t2v_w    = (const float*)d_in[6];
  const float* t2v_b    = (const float*)d_in[7];
  const float* gw_ih    = (const float*)d_in[8];
  const float* gw_hh    = (const float*)d_in[9];
  const float* gb_ih    = (const float*)d_in[10];
  const float* gb_hh    = (const float*)d_in[11];
  const float* w_q      = (const float*)d_in[12];
  const float* w_k      = (const float*)d_in[13];
  const float* w_v      = (const float*)d_in[14];
  const float* w_out    = (const float*)d_in[15];
  const float* b_out    = (const float*)d_in[16];
  const float* lp_sw    = (const float*)d_in[17];
  const float* lp_sb    = (const float*)d_in[18];
  const float* lp_dw    = (const float*)d_in[19];
  const float* lp_db    = (const float*)d_in[20];
  const float* lp_ow    = (const float*)d_in[21];
  const float* lp_ob    = (const float*)d_in[22];
  const int*   unids    = (const int*)d_in[23];
  const int*   nids     = (const int*)d_in[24];
  const int*   nbrn     = (const int*)d_in[25];
  const int*   nbrm     = (const int*)d_in[26];

  char* ws = (char*)d_ws;
  unsigned short* memb    = (unsigned short*)ws;                //  51,200,000 B
  unsigned short* f2v     = (unsigned short*)(ws + 51200000);   //  76,840,960
  unsigned short* A1      = (unsigned short*)(ws + 128040960);  //  83,279,872
  unsigned short* W1b     = (unsigned short*)(ws + 211320832);  //   1,277,952
  unsigned short* W2b     = (unsigned short*)(ws + 212598784);  //     393,216
  unsigned short* Gi_bf   = (unsigned short*)(ws + 212992000);  //  76,873,728
  unsigned short* Gh_bf   = (unsigned short*)(ws + 289865728);  //  76,873,728
  unsigned short* kvf_bf  = (unsigned short*)(ws + 366739456);  // 122,945,536
  unsigned short* qin_bf  = (unsigned short*)(ws + 489684992);  //   4,620,288
  float*          qv_f    = (float*)(ws + 494305280);           //   6,160,384
  unsigned short* wq_bf   = (unsigned short*)(ws + 500465664);  //     196,608
  unsigned short* wkv_bf  = (unsigned short*)(ws + 500662272);  //     589,824
  unsigned short* aonf_bf = (unsigned short*)(ws + 501252096);  //   6,160,384
  unsigned short* wo_bf   = (unsigned short*)(ws + 507412480);  //     262,144
  unsigned short* z_bf    = (unsigned short*)(ws + 507674624);  //   3,080,192
  unsigned short* wlp_bf  = (unsigned short*)(ws + 510754816);  //     262,144
  float*          P_f     = (float*)(ws + 511016960);           //  12,320,768
                                                                // end 523,337,728
  cvt_big2<<<2048, 256, 0, stream>>>(memory, umsg, memb, A1);
  cvt_weights<<<728, 256, 0, stream>>>(gw_ih, gw_hh, w_q, w_k, w_v, w_out,
                                       lp_sw, lp_dw,
                                       W1b, W2b, wq_bf, wkv_bf, wo_bf, wlp_bf);

  // --- GRU as bf16 MFMA GEMMs ---
  gemm_bt<1,0><<<(kMPAD/128)*6, 256, 0, stream>>>(
      A1, kKP1, nullptr, 13, kMPAD, A1, kKP1, W1b, kKP1,
      Gi_bf, nullptr, 13, 6, kGN);
  gemm_bt<1,0><<<(kMPAD/128)*6, 256, 0, stream>>>(
      memb, kDM, unids, 4, kU, memb, kDM, W2b, kDM,
      Gh_bf, nullptr, 4, 6, kGN);
  gru_gate_bf<<<kU, 256, 0, stream>>>(Gi_bf, Gh_bf, memory, gb_ih, gb_hh,
                                      unids, memb);

  // --- attention staging (f2v + qin merged) ---
  build_both<<<4096, 256, 0, stream>>>(nbr_f, nbr_t, times, last_upd, nids,
                                       t2v_w, t2v_b, memb, f2v, qin_bf);

  // q projection
  gemm_bt<0,0><<<(kNBPAD/128)*2, 256, 0, stream>>>(
      qin_bf, kQINP, nullptr, 6, kNBPAD, qin_bf, kQINP, wq_bf, kQINP,
      qv_f, nullptr, 6, 2, kDEMB);
  // kv projection with fused virtual k_in: memb-gather (ktiles 0-3) + f2v
  gemm_bt<1,0><<<(kNKPAD/128)*4, 256, 0, stream>>>(
      memb, kDM, nbrn, 4, kNKROWS, f2v, kF2V, wkv_bf, kKVLD,
      kvf_bf, nullptr, 9, 4, kZIN);
  attn2_kernel<<<kNB, 256, 0, stream>>>(qv_f, kvf_bf, qin_bf, nbrm, aonf_bf);
  // z then link-pred projections P = z @ [spw;dpw]^T
  gemm_bt<1,1><<<(kNBPAD/128)*2, 256, 0, stream>>>(
      aonf_bf, kZIN, nullptr, 8, kNBPAD, aonf_bf, kZIN, wo_bf, kZIN,
      z_bf, b_out, 8, 2, kDEMB);
  gemm_bt<0,0><<<(kNBPAD/128)*4, 256, 0, stream>>>(
      z_bf, kDEMB, nullptr, 4, kNBPAD, z_bf, kDEMB, wlp_bf, kDEMB,
      P_f, nullptr, 4, 4, kZIN);
  lp_small<<<4000, 256, 0, stream>>>(P_f, lp_sb, lp_db, lp_ow, lp_ob,
                                     (float*)d_out);
}